// Round 3
// baseline (303.606 us; speedup 1.0000x reference)
//
#include <hip/hip_runtime.h>

// YOLO loss: N=4096, S=14, B=2, NCLS=20. Cells = 802816.
// R3 (= R2 design, compile fix): LDS-staged coalesced loads. Pred 120B/cell +
// tcls 80B/cell are AoS; direct per-thread loads cost ~64 cache lines per
// wave-load-instruction -> transaction-bound at 68us regardless of L3/HBM
// residency. Block of 256 threads stages its contiguous 30KB pred + 20KB tcls
// slab via float4, then reads per-cell fields from LDS (stride-30 float2 = 
// 2-way bank alias = free; stride-20 float4 = 4-way, minor).
// 50KB LDS -> 3 blocks/CU. Dispatches: (zero+detect), (main + fused finalize).

#define NCELLS (4096 * 14 * 14)
#define TPB 256
#define NBLOCKS (NCELLS / TPB)  // 3136, exact

// ws layout (floats): [0..3] sums (cls,noobj,contain,reg); [4] block counter
// (uint); [8] mask-mode flag (int).

__global__ void yolo_init_kernel(float* ws, const unsigned char* mb) {
    if (threadIdx.x < 16) ws[threadIdx.x] = 0.0f;
    __syncthreads();
    // Detect mask layout: int32 {0,1} has bytes 4k+1..4k+3 == 0; random bool8
    // doesn't. Scan first 4096 slots (16KB; both layouts exceed that).
    int t = threadIdx.x;
    unsigned int found = 0;
#pragma unroll
    for (int k = 0; k < 16; ++k) {
        int slot = t * 16 + k;
        found |= mb[4 * slot + 1] | mb[4 * slot + 2] | mb[4 * slot + 3];
    }
    if (found) atomicOr((int*)(ws + 8), 1);  // 1 => bool8 layout
}

__global__ __launch_bounds__(256) void yolo_main_kernel(
    const float* __restrict__ pred,
    const float* __restrict__ tbox,
    const float* __restrict__ tcls,
    const void* __restrict__ mask,
    float* ws,
    float* __restrict__ out) {
    __shared__ float sp[TPB * 30];  // 30720 B, block's pred slab
    __shared__ float sc[TPB * 20];  // 20480 B, block's tcls slab
    const int tid = threadIdx.x;
    const int blk = blockIdx.x;
    const int c = blk * TPB + tid;

    // ---- coalesced staging: global float4 -> LDS ----
    {
        const float4* gp = (const float4*)(pred + (size_t)blk * (TPB * 30));
        float4* lp = (float4*)sp;  // 1920 float4 per block
#pragma unroll
        for (int j = 0; j < 7; ++j) lp[tid + 256 * j] = gp[tid + 256 * j];
        if (tid < 128) lp[tid + 1792] = gp[tid + 1792];
        const float4* gc = (const float4*)(tcls + (size_t)blk * (TPB * 20));
        float4* lc = (float4*)sc;  // 1280 float4 per block
#pragma unroll
        for (int j = 0; j < 5; ++j) lc[tid + 256 * j] = gc[tid + 256 * j];
    }

    // ---- direct (already-coalesced) loads ----
    const float4 tb = ((const float4*)tbox)[c];
    const int mode = ((const int*)(ws + 8))[0];  // uniform
    float m;
    if (mode) {
        m = ((const unsigned char*)mask)[c] ? 1.0f : 0.0f;
    } else {
        m = ((const int*)mask)[c] ? 1.0f : 0.0f;
    }

    __syncthreads();

    // ---- per-cell fields from LDS ----
    float pv[30];
    {
        const float2* p2 = (const float2*)(sp + tid * 30);  // 8B-aligned
#pragma unroll
        for (int k = 0; k < 15; ++k) {
            float2 t = p2[k];
            pv[2 * k] = t.x;
            pv[2 * k + 1] = t.y;
        }
    }
    float tc[20];
    {
        const float4* c4 = (const float4*)(sc + tid * 20);  // 16B-aligned
#pragma unroll
        for (int k = 0; k < 5; ++k) {
            float4 t = c4[k];
            tc[4 * k] = t.x;
            tc[4 * k + 1] = t.y;
            tc[4 * k + 2] = t.z;
            tc[4 * k + 3] = t.w;
        }
    }

    // ---- per-cell losses ----
    float s = 0.0f;
#pragma unroll
    for (int i = 0; i < 20; ++i) {
        float d = pv[10 + i] - tc[i];
        s += d * d;
    }
    float cls_s = m * s;

    float conf0 = pv[4], conf1 = pv[9];
    float noobj_s = (1.0f - m) * (conf0 * conf0 + conf1 * conf1);

    float iou[2];
    float at = (tb.z - tb.x) * (tb.w - tb.y);
#pragma unroll
    for (int b = 0; b < 2; ++b) {
        int base = 5 * b;
        float x = pv[base] * (1.0f / 14.0f);
        float y = pv[base + 1] * (1.0f / 14.0f);
        float w = pv[base + 2];
        float h = pv[base + 3];
        float p1x = x - w * 0.5f, p1y = y - h * 0.5f;
        float p2x = x + w * 0.5f, p2y = y + h * 0.5f;
        float ltx = fmaxf(p1x, tb.x), lty = fmaxf(p1y, tb.y);
        float rbx = fminf(p2x, tb.z), rby = fminf(p2y, tb.w);
        float iw = fmaxf(rbx - ltx, 0.0f), ih = fmaxf(rby - lty, 0.0f);
        float inter = iw * ih;
        float ap = w * h;
        iou[b] = inter / (ap + at - inter);
    }
    int best = (iou[1] > iou[0]) ? 5 : 0;  // jnp.argmax: first max wins
    float bx = pv[best], by = pv[best + 1], bw = pv[best + 2],
          bh = pv[best + 3], bc = pv[best + 4];

    float contain_s = m * (bc - 1.0f) * (bc - 1.0f);

    float dx = bx - tb.x, dy = by - tb.y;
    float dw = sqrtf(bw) - sqrtf(tb.z);
    float dh = sqrtf(bh) - sqrtf(tb.w);
    float reg_s = m * (dx * dx + dy * dy + dw * dw + dh * dh);

    // ---- reduction: wave64 shuffle -> LDS -> atomicAdd ----
#pragma unroll
    for (int off = 32; off > 0; off >>= 1) {
        cls_s += __shfl_down(cls_s, off, 64);
        noobj_s += __shfl_down(noobj_s, off, 64);
        contain_s += __shfl_down(contain_s, off, 64);
        reg_s += __shfl_down(reg_s, off, 64);
    }
    __shared__ float red[4][4];
    int lane = tid & 63;
    int wid = tid >> 6;
    if (lane == 0) {
        red[wid][0] = cls_s;
        red[wid][1] = noobj_s;
        red[wid][2] = contain_s;
        red[wid][3] = reg_s;
    }
    __syncthreads();
    if (tid < 4) {
        float v = red[0][tid] + red[1][tid] + red[2][tid] + red[3][tid];
        atomicAdd(&ws[tid], v);
    }
    __syncthreads();  // all 4 sum-atomics of this block precede the counter

    // ---- last-block finalize (fence + counter, device-scope) ----
    if (tid == 0) {
        __threadfence();
        unsigned int prev = atomicAdd((unsigned int*)(ws + 4), 1u);
        if (prev == (unsigned int)(NBLOCKS - 1)) {
            __threadfence();
            const float inv_n = 1.0f / 4096.0f;
            // atomic reads (add 0) -> device-scope, bypass stale L1
            float cls = atomicAdd(&ws[0], 0.0f) * inv_n;
            float noobj = atomicAdd(&ws[1], 0.0f) * inv_n;
            float contain = atomicAdd(&ws[2], 0.0f) * inv_n;
            float reg = atomicAdd(&ws[3], 0.0f) * inv_n;
            out[0] = cls + 0.5f * noobj + 5.0f * reg + contain;
            out[1] = reg;
            out[2] = contain;
            out[3] = noobj;
            out[4] = cls;
        }
    }
}

extern "C" void kernel_launch(void* const* d_in, const int* in_sizes, int n_in,
                              void* d_out, int out_size, void* d_ws,
                              size_t ws_size, hipStream_t stream) {
    const float* pred = (const float*)d_in[0];
    const float* tbox = (const float*)d_in[1];
    const float* tcls = (const float*)d_in[2];
    const void* mask = d_in[3];
    float* ws = (float*)d_ws;
    float* out = (float*)d_out;

    yolo_init_kernel<<<1, 256, 0, stream>>>(ws, (const unsigned char*)mask);
    yolo_main_kernel<<<NBLOCKS, TPB, 0, stream>>>(pred, tbox, tcls, mask, ws,
                                                  out);
}